// Round 1
// baseline (962.947 us; speedup 1.0000x reference)
//
#include <hip/hip_runtime.h>
#include <cstdint>

// GAT 2-layer: N=50000 nodes, E=800000 edges
// L1: IN=128 -> H1=8 x HID=64 (512), ELU, L2: 512 -> 1 x 64
#define NN 50000
#define NE 800000

__device__ __forceinline__ float warp_sum(float v) {
  #pragma unroll
  for (int s = 32; s; s >>= 1) v += __shfl_xor(v, s);
  return v;
}

__device__ __forceinline__ float lrelu(float x) { return x > 0.f ? x : 0.2f * x; }

// ---------------- GEMM: C[M,N] = A[M,K] @ B[K,N], optional ELU on A ----------
template<bool ELU>
__global__ __launch_bounds__(256)
void gemm_kernel(const float* __restrict__ A, const float* __restrict__ B,
                 float* __restrict__ C, int M, int K, int N) {
  __shared__ float As[16][66];   // [k][m], padded
  __shared__ float Bs[16][64];   // [k][n]
  const int t = threadIdx.x;
  const int row0 = blockIdx.x * 64, col0 = blockIdx.y * 64;
  const int tx = t & 15, ty = t >> 4;
  const int arow = t >> 2, acol = (t & 3) * 4;
  const int brow = t >> 4, bcol = (t & 15) * 4;
  float acc[4][4] = {};
  for (int kk = 0; kk < K; kk += 16) {
    float4 av = make_float4(0.f, 0.f, 0.f, 0.f);
    int gr = row0 + arow;
    if (gr < M) av = *(const float4*)(A + (size_t)gr * K + kk + acol);
    if (ELU) {
      av.x = av.x > 0.f ? av.x : __expf(av.x) - 1.f;
      av.y = av.y > 0.f ? av.y : __expf(av.y) - 1.f;
      av.z = av.z > 0.f ? av.z : __expf(av.z) - 1.f;
      av.w = av.w > 0.f ? av.w : __expf(av.w) - 1.f;
    }
    As[acol + 0][arow] = av.x;
    As[acol + 1][arow] = av.y;
    As[acol + 2][arow] = av.z;
    As[acol + 3][arow] = av.w;
    *(float4*)&Bs[brow][bcol] = *(const float4*)(B + (size_t)(kk + brow) * N + col0 + bcol);
    __syncthreads();
    #pragma unroll
    for (int k = 0; k < 16; ++k) {
      float a[4];
      #pragma unroll
      for (int i = 0; i < 4; ++i) a[i] = As[k][ty * 4 + i];
      float4 b = *(const float4*)&Bs[k][tx * 4];
      #pragma unroll
      for (int i = 0; i < 4; ++i) {
        acc[i][0] += a[i] * b.x; acc[i][1] += a[i] * b.y;
        acc[i][2] += a[i] * b.z; acc[i][3] += a[i] * b.w;
      }
    }
    __syncthreads();
  }
  #pragma unroll
  for (int i = 0; i < 4; ++i) {
    int gr = row0 + ty * 4 + i;
    if (gr < M) {
      float4 v = make_float4(acc[i][0], acc[i][1], acc[i][2], acc[i][3]);
      *(float4*)(C + (size_t)gr * N + col0 + tx * 4) = v;
    }
  }
}

// ------------- el/er: per-node attention logits; wave per node ---------------
template<int H>
__global__ __launch_bounds__(256)
void el_er_kernel(const float* __restrict__ feat, const float* __restrict__ al,
                  const float* __restrict__ ar, float* __restrict__ el,
                  float* __restrict__ er, int N) {
  int n = blockIdx.x * 4 + (threadIdx.x >> 6);
  if (n >= N) return;
  int l = threadIdx.x & 63;
  const float* fr = feat + (size_t)n * (H * 64);
  #pragma unroll
  for (int h = 0; h < H; ++h) {
    float v = fr[h * 64 + l];
    float pl = warp_sum(v * al[h * 64 + l]);
    float pr = warp_sum(v * ar[h * 64 + l]);
    if (l == 0) { el[n * H + h] = pl; er[n * H + h] = pr; }
  }
}

// ---------------- CSR build: histogram -> scan -> scatter --------------------
__global__ void hist_kernel(const int* __restrict__ dst, int* __restrict__ cnt, int E) {
  int e = blockIdx.x * 256 + threadIdx.x;
  if (e < E) atomicAdd(&cnt[dst[e]], 1);
}

__global__ __launch_bounds__(1024)
void scan_kernel(const int* __restrict__ cnt, int* __restrict__ rowptr, int N) {
  __shared__ int sums[1024];
  int t = threadIdx.x;
  const int CH = (N + 1023) / 1024;
  int s0 = t * CH, s1 = s0 + CH; if (s1 > N) s1 = N;
  int s = 0;
  for (int i = s0; i < s1; ++i) s += cnt[i];
  sums[t] = s;
  __syncthreads();
  for (int d = 1; d < 1024; d <<= 1) {
    int v = sums[t];
    int u = (t >= d) ? sums[t - d] : 0;
    __syncthreads();
    sums[t] = v + u;
    __syncthreads();
  }
  int run = (t == 0) ? 0 : sums[t - 1];
  for (int i = s0; i < s1; ++i) { rowptr[i] = run; run += cnt[i]; }
  if (t == 1023) rowptr[N] = sums[1023];
}

__global__ void scatter_kernel(const int* __restrict__ dst, const int* __restrict__ rowptr,
                               int* __restrict__ fill, int* __restrict__ eidx, int E) {
  int e = blockIdx.x * 256 + threadIdx.x;
  if (e >= E) return;
  int d = dst[e];
  int pos = atomicAdd(&fill[d], 1);
  eidx[rowptr[d] + pos] = e;
}

// ---------------- per-edge raw attention scores ------------------------------
template<int H>
__global__ void edge_e_kernel(const float* __restrict__ el, const float* __restrict__ er,
                              const int* __restrict__ src, const int* __restrict__ dst,
                              float* __restrict__ ebuf, int E) {
  int e = blockIdx.x * 256 + threadIdx.x;
  if (e >= E) return;
  int s = src[e], d = dst[e];
  if constexpr (H == 8) {
    float4 l0 = *(const float4*)(el + (size_t)s * 8);
    float4 l1 = *(const float4*)(el + (size_t)s * 8 + 4);
    float4 r0 = *(const float4*)(er + (size_t)d * 8);
    float4 r1 = *(const float4*)(er + (size_t)d * 8 + 4);
    float4 v0, v1;
    v0.x = lrelu(l0.x + r0.x); v0.y = lrelu(l0.y + r0.y);
    v0.z = lrelu(l0.z + r0.z); v0.w = lrelu(l0.w + r0.w);
    v1.x = lrelu(l1.x + r1.x); v1.y = lrelu(l1.y + r1.y);
    v1.z = lrelu(l1.z + r1.z); v1.w = lrelu(l1.w + r1.w);
    *(float4*)(ebuf + (size_t)e * 8) = v0;
    *(float4*)(ebuf + (size_t)e * 8 + 4) = v1;
  } else {
    ebuf[e] = lrelu(el[s] + er[d]);
  }
}

// ------------- layer-1 aggregate: wave per node, 8 heads x 64 ---------------
// lane owns channels [lane*8, lane*8+8) -> single head lane>>3. No cross-lane
// reductions needed: every lane of a head-group sees every edge's e-value.
__global__ __launch_bounds__(256)
void agg1_kernel(const float* __restrict__ feat, const float* __restrict__ ebuf,
                 const int* __restrict__ src, const int* __restrict__ rowptr,
                 const int* __restrict__ eidx, const float* __restrict__ bias,
                 float* __restrict__ out, int N) {
  int n = blockIdx.x * 4 + (threadIdx.x >> 6);
  if (n >= N) return;
  int lane = threadIdx.x & 63;
  int p0 = rowptr[n], p1 = rowptr[n + 1];
  int myh = lane >> 3;
  float m = -3.4e38f;
  for (int i = p0; i < p1; ++i) {
    int e = eidx[i];
    m = fmaxf(m, ebuf[(size_t)e * 8 + myh]);
  }
  float z = 0.f;
  for (int i = p0; i < p1; ++i) {
    int e = eidx[i];
    z += __expf(ebuf[(size_t)e * 8 + myh] - m);
  }
  float iz = (p1 > p0) ? 1.f / z : 0.f;
  float4 a0 = make_float4(0.f, 0.f, 0.f, 0.f), a1 = a0;
  for (int i = p0; i < p1; ++i) {
    int e = eidx[i];
    int s = src[e];
    float w = __expf(ebuf[(size_t)e * 8 + myh] - m) * iz;
    const float4* fp = (const float4*)(feat + (size_t)s * 512 + lane * 8);
    float4 f0 = fp[0], f1 = fp[1];
    a0.x += f0.x * w; a0.y += f0.y * w; a0.z += f0.z * w; a0.w += f0.w * w;
    a1.x += f1.x * w; a1.y += f1.y * w; a1.z += f1.z * w; a1.w += f1.w * w;
  }
  const float4* bp = (const float4*)(bias + lane * 8);
  float4 b0 = bp[0], b1 = bp[1];
  a0.x += b0.x; a0.y += b0.y; a0.z += b0.z; a0.w += b0.w;
  a1.x += b1.x; a1.y += b1.y; a1.z += b1.z; a1.w += b1.w;
  float4* op = (float4*)(out + (size_t)n * 512 + lane * 8);
  op[0] = a0; op[1] = a1;
}

// ------------- layer-2 aggregate: wave per node, 1 head x 64 ----------------
__global__ __launch_bounds__(256)
void agg2_kernel(const float* __restrict__ feat, const float* __restrict__ ebuf,
                 const int* __restrict__ src, const int* __restrict__ rowptr,
                 const int* __restrict__ eidx, const float* __restrict__ bias,
                 float* __restrict__ out, int N) {
  int n = blockIdx.x * 4 + (threadIdx.x >> 6);
  if (n >= N) return;
  int lane = threadIdx.x & 63;
  int p0 = rowptr[n], p1 = rowptr[n + 1];
  float m = -3.4e38f;
  for (int i = p0; i < p1; ++i) m = fmaxf(m, ebuf[eidx[i]]);
  float z = 0.f;
  for (int i = p0; i < p1; ++i) z += __expf(ebuf[eidx[i]] - m);
  float iz = (p1 > p0) ? 1.f / z : 0.f;
  float acc = 0.f;
  for (int i = p0; i < p1; ++i) {
    int e = eidx[i];
    int s = src[e];
    float w = __expf(ebuf[e] - m) * iz;
    acc += feat[(size_t)s * 64 + lane] * w;
  }
  out[(size_t)n * 64 + lane] = acc + bias[lane];
}

extern "C" void kernel_launch(void* const* d_in, const int* in_sizes, int n_in,
                              void* d_out, int out_size, void* d_ws, size_t ws_size,
                              hipStream_t stream) {
  const float* x   = (const float*)d_in[0];
  const int*   src = (const int*)d_in[1];
  const int*   dst = (const int*)d_in[2];
  const float* W1  = (const float*)d_in[3];
  const float* al1 = (const float*)d_in[4];
  const float* ar1 = (const float*)d_in[5];
  const float* b1  = (const float*)d_in[6];
  const float* W2  = (const float*)d_in[7];
  const float* al2 = (const float*)d_in[8];
  const float* ar2 = (const float*)d_in[9];
  const float* b2  = (const float*)d_in[10];
  float* out = (float*)d_out;

  char* p = (char*)d_ws;
  auto alloc = [&](size_t bytes) { void* r = (void*)p; p += (bytes + 255) & ~(size_t)255; return r; };
  float* feat1 = (float*)alloc((size_t)NN * 512 * 4);   // 102.4 MB
  float* out1  = (float*)alloc((size_t)NN * 512 * 4);   // 102.4 MB
  float* el1   = (float*)alloc((size_t)NN * 8 * 4);
  float* er1   = (float*)alloc((size_t)NN * 8 * 4);
  float* ebuf1 = (float*)alloc((size_t)NE * 8 * 4);     // 25.6 MB
  float* feat2 = (float*)alloc((size_t)NN * 64 * 4);    // 12.8 MB
  float* el2   = (float*)alloc((size_t)NN * 4);
  float* er2   = (float*)alloc((size_t)NN * 4);
  float* ebuf2 = (float*)alloc((size_t)NE * 4);
  int* rowptr  = (int*)alloc((size_t)(NN + 1) * 4);
  int* eidx    = (int*)alloc((size_t)NE * 4);
  int* cnt     = (int*)alloc((size_t)NN * 4);
  int* fill    = (int*)alloc((size_t)NN * 4);

  hipMemsetAsync(cnt, 0, (size_t)NN * 4, stream);
  hipMemsetAsync(fill, 0, (size_t)NN * 4, stream);

  // ---- layer 1 ----
  dim3 g1((NN + 63) / 64, 8);
  gemm_kernel<false><<<g1, 256, 0, stream>>>(x, W1, feat1, NN, 128, 512);
  el_er_kernel<8><<<(NN + 3) / 4, 256, 0, stream>>>(feat1, al1, ar1, el1, er1, NN);
  // CSR by dst (graph is shared by both layers)
  hist_kernel<<<(NE + 255) / 256, 256, 0, stream>>>(dst, cnt, NE);
  scan_kernel<<<1, 1024, 0, stream>>>(cnt, rowptr, NN);
  scatter_kernel<<<(NE + 255) / 256, 256, 0, stream>>>(dst, rowptr, fill, eidx, NE);
  edge_e_kernel<8><<<(NE + 255) / 256, 256, 0, stream>>>(el1, er1, src, dst, ebuf1, NE);
  agg1_kernel<<<(NN + 3) / 4, 256, 0, stream>>>(feat1, ebuf1, src, rowptr, eidx, b1, out1, NN);

  // ---- layer 2 (ELU fused into GEMM A-load) ----
  dim3 g2((NN + 63) / 64, 1);
  gemm_kernel<true><<<g2, 256, 0, stream>>>(out1, W2, feat2, NN, 512, 64);
  el_er_kernel<1><<<(NN + 3) / 4, 256, 0, stream>>>(feat2, al2, ar2, el2, er2, NN);
  edge_e_kernel<1><<<(NE + 255) / 256, 256, 0, stream>>>(el2, er2, src, dst, ebuf2, NE);
  agg2_kernel<<<(NN + 3) / 4, 256, 0, stream>>>(feat2, ebuf2, src, rowptr, eidx, b2, out, NN);
}

// Round 2
// 646.066 us; speedup vs baseline: 1.4905x; 1.4905x over previous
//
#include <hip/hip_runtime.h>
#include <cstdint>

// GAT 2-layer: N=50000 nodes, E=800000 edges
// L1: 128 -> 8 heads x 64 (512), ELU, L2: 512 -> 1 x 64
#define NN 50000
#define NE 800000

__device__ __forceinline__ float lrelu(float x) { return x > 0.f ? x : 0.2f * x; }
__device__ __forceinline__ float elu(float x) { return x > 0.f ? x : __expf(x) - 1.f; }

// ============ GEMM1: feat1 = x @ W1  [50000,128]x[128,512], fused el1/er1 ====
// BM=128 BN=128 BK=16, 256 threads, 8x8 micro-tile
__global__ __launch_bounds__(256)
void gemm1_kernel(const float* __restrict__ A, const float* __restrict__ B,
                  const float* __restrict__ al, const float* __restrict__ ar,
                  float* __restrict__ C, float* __restrict__ el, float* __restrict__ er) {
  const int M = NN, K = 128, N = 512;
  __shared__ float As[16][132];
  __shared__ float Bs[16][128];
  const int t = threadIdx.x;
  const int row0 = blockIdx.x * 128, col0 = blockIdx.y * 128;
  const int tx = t & 15, ty = t >> 4;
  const int arr = t >> 2, ac4 = (t & 3) * 4;
  float acc[8][8] = {};
  for (int kk = 0; kk < K; kk += 16) {
    #pragma unroll
    for (int h = 0; h < 2; ++h) {
      int r = arr + h * 64;
      int gr = row0 + r;
      float4 av = make_float4(0.f, 0.f, 0.f, 0.f);
      if (gr < M) av = *(const float4*)(A + (size_t)gr * K + kk + ac4);
      As[ac4 + 0][r] = av.x; As[ac4 + 1][r] = av.y;
      As[ac4 + 2][r] = av.z; As[ac4 + 3][r] = av.w;
    }
    #pragma unroll
    for (int h = 0; h < 2; ++h) {
      int idx = t + h * 256;
      int r = idx >> 5, c4 = (idx & 31) * 4;
      *(float4*)&Bs[r][c4] = *(const float4*)(B + (size_t)(kk + r) * N + col0 + c4);
    }
    __syncthreads();
    #pragma unroll
    for (int k = 0; k < 16; ++k) {
      float a[8], b[8];
      *(float4*)&a[0] = *(const float4*)&As[k][ty * 8];
      *(float4*)&a[4] = *(const float4*)&As[k][ty * 8 + 4];
      *(float4*)&b[0] = *(const float4*)&Bs[k][tx * 8];
      *(float4*)&b[4] = *(const float4*)&Bs[k][tx * 8 + 4];
      #pragma unroll
      for (int i = 0; i < 8; ++i)
        #pragma unroll
        for (int j = 0; j < 8; ++j)
          acc[i][j] = fmaf(a[i], b[j], acc[i][j]);
    }
    __syncthreads();
  }
  // epilogue: store C + fused el/er (block's 128 cols = 2 complete heads)
  const int head = (col0 >> 6) + (tx >> 3);
  float alf[8], arf[8];
  #pragma unroll
  for (int j = 0; j < 8; ++j) {
    alf[j] = al[head * 64 + (tx & 7) * 8 + j];
    arf[j] = ar[head * 64 + (tx & 7) * 8 + j];
  }
  #pragma unroll
  for (int i = 0; i < 8; ++i) {
    int gr = row0 + ty * 8 + i;
    float pl = 0.f, pr = 0.f;
    #pragma unroll
    for (int j = 0; j < 8; ++j) {
      pl = fmaf(acc[i][j], alf[j], pl);
      pr = fmaf(acc[i][j], arf[j], pr);
    }
    #pragma unroll
    for (int s = 1; s <= 4; s <<= 1) { pl += __shfl_xor(pl, s); pr += __shfl_xor(pr, s); }
    if (gr < M) {
      *(float4*)(C + (size_t)gr * N + col0 + tx * 8) =
          make_float4(acc[i][0], acc[i][1], acc[i][2], acc[i][3]);
      *(float4*)(C + (size_t)gr * N + col0 + tx * 8 + 4) =
          make_float4(acc[i][4], acc[i][5], acc[i][6], acc[i][7]);
      if ((tx & 7) == 0) { el[gr * 8 + head] = pl; er[gr * 8 + head] = pr; }
    }
  }
}

// ============ GEMM2: feat2 = ELU(out1) @ W2  [50000,512]x[512,64], el2/er2 ===
// BM=128 BN=64 BK=32, 256 threads, 8x4 micro-tile
__global__ __launch_bounds__(256)
void gemm2_kernel(const float* __restrict__ A, const float* __restrict__ B,
                  const float* __restrict__ al, const float* __restrict__ ar,
                  float* __restrict__ C, float* __restrict__ el, float* __restrict__ er) {
  const int M = NN, K = 512, N = 64;
  __shared__ float As[32][132];
  __shared__ float Bs[32][64];
  const int t = threadIdx.x;
  const int row0 = blockIdx.x * 128;
  const int tx = t & 15, ty = t >> 4;
  float acc[8][4] = {};
  for (int kk = 0; kk < K; kk += 32) {
    #pragma unroll
    for (int h = 0; h < 4; ++h) {
      int idx = t + h * 256;
      int r = idx >> 3, c4 = (idx & 7) * 4;
      int gr = row0 + r;
      float4 av = make_float4(0.f, 0.f, 0.f, 0.f);
      if (gr < M) av = *(const float4*)(A + (size_t)gr * K + kk + c4);
      av.x = elu(av.x); av.y = elu(av.y); av.z = elu(av.z); av.w = elu(av.w);
      As[c4 + 0][r] = av.x; As[c4 + 1][r] = av.y;
      As[c4 + 2][r] = av.z; As[c4 + 3][r] = av.w;
    }
    #pragma unroll
    for (int h = 0; h < 2; ++h) {
      int idx = t + h * 256;
      int r = idx >> 4, c4 = (idx & 15) * 4;
      *(float4*)&Bs[r][c4] = *(const float4*)(B + (size_t)(kk + r) * N + c4);
    }
    __syncthreads();
    #pragma unroll
    for (int k = 0; k < 32; ++k) {
      float a[8];
      *(float4*)&a[0] = *(const float4*)&As[k][ty * 8];
      *(float4*)&a[4] = *(const float4*)&As[k][ty * 8 + 4];
      float4 b = *(const float4*)&Bs[k][tx * 4];
      #pragma unroll
      for (int i = 0; i < 8; ++i) {
        acc[i][0] = fmaf(a[i], b.x, acc[i][0]);
        acc[i][1] = fmaf(a[i], b.y, acc[i][1]);
        acc[i][2] = fmaf(a[i], b.z, acc[i][2]);
        acc[i][3] = fmaf(a[i], b.w, acc[i][3]);
      }
    }
    __syncthreads();
  }
  float alf[4], arf[4];
  #pragma unroll
  for (int j = 0; j < 4; ++j) { alf[j] = al[tx * 4 + j]; arf[j] = ar[tx * 4 + j]; }
  #pragma unroll
  for (int i = 0; i < 8; ++i) {
    int gr = row0 + ty * 8 + i;
    float pl = 0.f, pr = 0.f;
    #pragma unroll
    for (int j = 0; j < 4; ++j) {
      pl = fmaf(acc[i][j], alf[j], pl);
      pr = fmaf(acc[i][j], arf[j], pr);
    }
    #pragma unroll
    for (int s = 1; s <= 8; s <<= 1) { pl += __shfl_xor(pl, s); pr += __shfl_xor(pr, s); }
    if (gr < M) {
      *(float4*)(C + (size_t)gr * N + tx * 4) =
          make_float4(acc[i][0], acc[i][1], acc[i][2], acc[i][3]);
      if (tx == 0) { el[gr] = pl; er[gr] = pr; }
    }
  }
}

// ===================== CSR build (by dst) ====================================
__global__ void hist_kernel(const int* __restrict__ dst, int* __restrict__ cnt, int E) {
  int e = blockIdx.x * 256 + threadIdx.x;
  if (e < E) atomicAdd(&cnt[dst[e]], 1);
}

__global__ __launch_bounds__(1024)
void scan_kernel(const int* __restrict__ cnt, int* __restrict__ rowptr, int N) {
  __shared__ int sums[1024];
  int t = threadIdx.x;
  const int CH = (N + 1023) / 1024;
  int s0 = t * CH, s1 = s0 + CH; if (s1 > N) s1 = N;
  int s = 0;
  for (int i = s0; i < s1; ++i) s += cnt[i];
  sums[t] = s;
  __syncthreads();
  for (int d = 1; d < 1024; d <<= 1) {
    int v = sums[t];
    int u = (t >= d) ? sums[t - d] : 0;
    __syncthreads();
    sums[t] = v + u;
    __syncthreads();
  }
  int run = (t == 0) ? 0 : sums[t - 1];
  for (int i = s0; i < s1; ++i) { rowptr[i] = run; run += cnt[i]; }
  if (t == 1023) rowptr[N] = sums[1023];
}

// also writes src in CSR order -> kills one gather level downstream
__global__ void scatter_kernel(const int* __restrict__ dst, const int* __restrict__ src,
                               const int* __restrict__ rowptr, int* __restrict__ fill,
                               int* __restrict__ srcs, int E) {
  int e = blockIdx.x * 256 + threadIdx.x;
  if (e >= E) return;
  int d = dst[e];
  int pos = atomicAdd(&fill[d], 1);
  srcs[rowptr[d] + pos] = src[e];
}

// ============ attn1: walpha[i][h] = softmax per (dst-node, head) =============
// wave per node; lane = (j = lane>>3 edge-slot, h = lane&7 head)
__global__ __launch_bounds__(256)
void attn1_kernel(const float* __restrict__ el, const float* __restrict__ er,
                  const int* __restrict__ srcs, const int* __restrict__ rowptr,
                  float* __restrict__ wal, int N) {
  int n = blockIdx.x * 4 + (threadIdx.x >> 6);
  if (n >= N) return;
  int lane = threadIdx.x & 63;
  int j = lane >> 3, h = lane & 7;
  int p0 = rowptr[n], p1 = rowptr[n + 1];
  int deg = p1 - p0;
  if (deg == 0) return;
  float erh = er[(size_t)n * 8 + h];
  if (deg <= 64) {
    float vals[8];
    float m = -3.4e38f;
    #pragma unroll
    for (int st = 0; st < 8; ++st) {
      int i = p0 + st * 8 + j;
      float e = -3.4e38f;
      if (i < p1) e = lrelu(el[(size_t)srcs[i] * 8 + h] + erh);
      vals[st] = e;
      m = fmaxf(m, e);
    }
    m = fmaxf(m, __shfl_xor(m, 8));
    m = fmaxf(m, __shfl_xor(m, 16));
    m = fmaxf(m, __shfl_xor(m, 32));
    float z = 0.f;
    #pragma unroll
    for (int st = 0; st < 8; ++st) {
      float ev = __expf(vals[st] - m);   // inactive slots: exp(-huge)=0
      vals[st] = ev;
      z += ev;
    }
    z += __shfl_xor(z, 8); z += __shfl_xor(z, 16); z += __shfl_xor(z, 32);
    float iz = 1.f / z;
    #pragma unroll
    for (int st = 0; st < 8; ++st) {
      int i = p0 + st * 8 + j;
      if (i < p1) wal[(size_t)i * 8 + h] = vals[st] * iz;
    }
  } else {
    float m = -3.4e38f;
    for (int i = p0 + j; i < p1; i += 8)
      m = fmaxf(m, lrelu(el[(size_t)srcs[i] * 8 + h] + erh));
    m = fmaxf(m, __shfl_xor(m, 8));
    m = fmaxf(m, __shfl_xor(m, 16));
    m = fmaxf(m, __shfl_xor(m, 32));
    float z = 0.f;
    for (int i = p0 + j; i < p1; i += 8)
      z += __expf(lrelu(el[(size_t)srcs[i] * 8 + h] + erh) - m);
    z += __shfl_xor(z, 8); z += __shfl_xor(z, 16); z += __shfl_xor(z, 32);
    float iz = 1.f / z;
    for (int i = p0 + j; i < p1; i += 8)
      wal[(size_t)i * 8 + h] = __expf(lrelu(el[(size_t)srcs[i] * 8 + h] + erh) - m) * iz;
  }
}

// ============ attn2: single head ============================================
__global__ __launch_bounds__(256)
void attn2_kernel(const float* __restrict__ el, const float* __restrict__ er,
                  const int* __restrict__ srcs, const int* __restrict__ rowptr,
                  float* __restrict__ wal, int N) {
  int n = blockIdx.x * 4 + (threadIdx.x >> 6);
  if (n >= N) return;
  int lane = threadIdx.x & 63;
  int p0 = rowptr[n], p1 = rowptr[n + 1];
  int deg = p1 - p0;
  if (deg == 0) return;
  float ern = er[n];
  if (deg <= 256) {
    float vals[4];
    float m = -3.4e38f;
    #pragma unroll
    for (int st = 0; st < 4; ++st) {
      int i = p0 + st * 64 + lane;
      float e = -3.4e38f;
      if (i < p1) e = lrelu(el[srcs[i]] + ern);
      vals[st] = e;
      m = fmaxf(m, e);
    }
    #pragma unroll
    for (int s = 1; s <= 32; s <<= 1) m = fmaxf(m, __shfl_xor(m, s));
    float z = 0.f;
    #pragma unroll
    for (int st = 0; st < 4; ++st) {
      float ev = __expf(vals[st] - m);
      vals[st] = ev;
      z += ev;
    }
    #pragma unroll
    for (int s = 1; s <= 32; s <<= 1) z += __shfl_xor(z, s);
    float iz = 1.f / z;
    #pragma unroll
    for (int st = 0; st < 4; ++st) {
      int i = p0 + st * 64 + lane;
      if (i < p1) wal[i] = vals[st] * iz;
    }
  } else {
    float m = -3.4e38f;
    for (int i = p0 + lane; i < p1; i += 64)
      m = fmaxf(m, lrelu(el[srcs[i]] + ern));
    #pragma unroll
    for (int s = 1; s <= 32; s <<= 1) m = fmaxf(m, __shfl_xor(m, s));
    float z = 0.f;
    for (int i = p0 + lane; i < p1; i += 64)
      z += __expf(lrelu(el[srcs[i]] + ern) - m);
    #pragma unroll
    for (int s = 1; s <= 32; s <<= 1) z += __shfl_xor(z, s);
    float iz = 1.f / z;
    for (int i = p0 + lane; i < p1; i += 64)
      wal[i] = __expf(lrelu(el[srcs[i]] + ern) - m) * iz;
  }
}

// ============ agg1: out1[:, CO:CO+256] = sum alpha * feat1[src] + b ==========
// wave per node; lane owns 4 channels; two channel-passes keep the gathered
// half of feat1 (51 MB) + streams inside the 256 MB LLC.
template<int CO>
__global__ __launch_bounds__(256)
void agg1_kernel(const float* __restrict__ feat, const float* __restrict__ wal,
                 const int* __restrict__ srcs, const int* __restrict__ rowptr,
                 const float* __restrict__ bias, float* __restrict__ out, int N) {
  int n = blockIdx.x * 4 + (threadIdx.x >> 6);
  if (n >= N) return;
  int lane = threadIdx.x & 63;
  const int c = CO + lane * 4;
  const int myh = c >> 6;
  int p0 = rowptr[n], p1 = rowptr[n + 1];
  float4 acc = make_float4(0.f, 0.f, 0.f, 0.f);
  int i = p0;
  for (; i + 2 <= p1; i += 2) {
    int s0 = srcs[i], s1 = srcs[i + 1];
    float w0 = wal[(size_t)i * 8 + myh];
    float w1 = wal[(size_t)(i + 1) * 8 + myh];
    float4 f0 = *(const float4*)(feat + (size_t)s0 * 512 + c);
    float4 f1 = *(const float4*)(feat + (size_t)s1 * 512 + c);
    acc.x = fmaf(f0.x, w0, acc.x); acc.y = fmaf(f0.y, w0, acc.y);
    acc.z = fmaf(f0.z, w0, acc.z); acc.w = fmaf(f0.w, w0, acc.w);
    acc.x = fmaf(f1.x, w1, acc.x); acc.y = fmaf(f1.y, w1, acc.y);
    acc.z = fmaf(f1.z, w1, acc.z); acc.w = fmaf(f1.w, w1, acc.w);
  }
  if (i < p1) {
    int s0 = srcs[i];
    float w0 = wal[(size_t)i * 8 + myh];
    float4 f0 = *(const float4*)(feat + (size_t)s0 * 512 + c);
    acc.x = fmaf(f0.x, w0, acc.x); acc.y = fmaf(f0.y, w0, acc.y);
    acc.z = fmaf(f0.z, w0, acc.z); acc.w = fmaf(f0.w, w0, acc.w);
  }
  float4 b = *(const float4*)(bias + c);
  acc.x += b.x; acc.y += b.y; acc.z += b.z; acc.w += b.w;
  *(float4*)(out + (size_t)n * 512 + c) = acc;
}

// ============ agg2: out[n] = sum alpha * feat2[src] + b2 =====================
__global__ __launch_bounds__(256)
void agg2_kernel(const float* __restrict__ feat, const float* __restrict__ wal,
                 const int* __restrict__ srcs, const int* __restrict__ rowptr,
                 const float* __restrict__ bias, float* __restrict__ out, int N) {
  int n = blockIdx.x * 4 + (threadIdx.x >> 6);
  if (n >= N) return;
  int lane = threadIdx.x & 63;
  int p0 = rowptr[n], p1 = rowptr[n + 1];
  float acc = 0.f;
  int i = p0;
  for (; i + 2 <= p1; i += 2) {
    int s0 = srcs[i], s1 = srcs[i + 1];
    float w0 = wal[i], w1 = wal[i + 1];
    acc = fmaf(feat[(size_t)s0 * 64 + lane], w0, acc);
    acc = fmaf(feat[(size_t)s1 * 64 + lane], w1, acc);
  }
  if (i < p1)
    acc = fmaf(feat[(size_t)srcs[i] * 64 + lane], wal[i], acc);
  out[(size_t)n * 64 + lane] = acc + bias[lane];
}

extern "C" void kernel_launch(void* const* d_in, const int* in_sizes, int n_in,
                              void* d_out, int out_size, void* d_ws, size_t ws_size,
                              hipStream_t stream) {
  const float* x   = (const float*)d_in[0];
  const int*   src = (const int*)d_in[1];
  const int*   dst = (const int*)d_in[2];
  const float* W1  = (const float*)d_in[3];
  const float* al1 = (const float*)d_in[4];
  const float* ar1 = (const float*)d_in[5];
  const float* b1  = (const float*)d_in[6];
  const float* W2  = (const float*)d_in[7];
  const float* al2 = (const float*)d_in[8];
  const float* ar2 = (const float*)d_in[9];
  const float* b2  = (const float*)d_in[10];
  float* out = (float*)d_out;

  char* p = (char*)d_ws;
  auto alloc = [&](size_t bytes) { void* r = (void*)p; p += (bytes + 255) & ~(size_t)255; return r; };
  float* feat1 = (float*)alloc((size_t)NN * 512 * 4);
  float* out1  = (float*)alloc((size_t)NN * 512 * 4);
  float* el1   = (float*)alloc((size_t)NN * 8 * 4);
  float* er1   = (float*)alloc((size_t)NN * 8 * 4);
  float* wal1  = (float*)alloc((size_t)NE * 8 * 4);
  float* feat2 = (float*)alloc((size_t)NN * 64 * 4);
  float* el2   = (float*)alloc((size_t)NN * 4);
  float* er2   = (float*)alloc((size_t)NN * 4);
  float* wal2  = (float*)alloc((size_t)NE * 4);
  int* rowptr  = (int*)alloc((size_t)(NN + 1) * 4);
  int* srcs    = (int*)alloc((size_t)NE * 4);
  int* cnt     = (int*)alloc((size_t)NN * 4);
  int* fill    = (int*)alloc((size_t)NN * 4);

  hipMemsetAsync(cnt, 0, (size_t)NN * 4, stream);
  hipMemsetAsync(fill, 0, (size_t)NN * 4, stream);

  // CSR build (shared by both layers)
  hist_kernel<<<(NE + 255) / 256, 256, 0, stream>>>(dst, cnt, NE);
  scan_kernel<<<1, 1024, 0, stream>>>(cnt, rowptr, NN);
  scatter_kernel<<<(NE + 255) / 256, 256, 0, stream>>>(dst, src, rowptr, fill, srcs, NE);

  // layer 1
  gemm1_kernel<<<dim3(391, 4), 256, 0, stream>>>(x, W1, al1, ar1, feat1, el1, er1);
  attn1_kernel<<<(NN + 3) / 4, 256, 0, stream>>>(el1, er1, srcs, rowptr, wal1, NN);
  agg1_kernel<0><<<(NN + 3) / 4, 256, 0, stream>>>(feat1, wal1, srcs, rowptr, b1, out1, NN);
  agg1_kernel<256><<<(NN + 3) / 4, 256, 0, stream>>>(feat1, wal1, srcs, rowptr, b1, out1, NN);

  // layer 2
  gemm2_kernel<<<dim3(391, 1), 256, 0, stream>>>(out1, W2, al2, ar2, feat2, el2, er2);
  attn2_kernel<<<(NN + 3) / 4, 256, 0, stream>>>(el2, er2, srcs, rowptr, wal2, NN);
  agg2_kernel<<<(NN + 3) / 4, 256, 0, stream>>>(feat2, wal2, srcs, rowptr, b2, out, NN);
}

// Round 3
// 539.256 us; speedup vs baseline: 1.7857x; 1.1981x over previous
//
#include <hip/hip_runtime.h>
#include <cstdint>

// GAT 2-layer: N=50000 nodes, E=800000 edges
// L1: 128 -> 8 heads x 64 (512) [feat1 stored bf16], ELU, L2: 512 -> 1 x 64
#define NN 50000
#define NE 800000

__device__ __forceinline__ float lrelu(float x) { return x > 0.f ? x : 0.2f * x; }
__device__ __forceinline__ float elu(float x) { return x > 0.f ? x : __expf(x) - 1.f; }

__device__ __forceinline__ unsigned short f2bf(float f) {
  unsigned u = __float_as_uint(f);
  unsigned r = (u + 0x7FFFu + ((u >> 16) & 1u)) >> 16;   // RNE
  return (unsigned short)r;
}

// ============ GEMM1: feat1(bf16) = x @ W1  [50000,128]x[128,512], + el1/er1 ==
// BM=128 BN=128 BK=16, 256 threads, 8x8 micro-tile; f32 compute, bf16 store
__global__ __launch_bounds__(256)
void gemm1_kernel(const float* __restrict__ A, const float* __restrict__ B,
                  const float* __restrict__ al, const float* __restrict__ ar,
                  unsigned short* __restrict__ C, float* __restrict__ el,
                  float* __restrict__ er) {
  const int M = NN, K = 128, N = 512;
  __shared__ float As[16][132];
  __shared__ float Bs[16][128];
  const int t = threadIdx.x;
  const int row0 = blockIdx.x * 128, col0 = blockIdx.y * 128;
  const int tx = t & 15, ty = t >> 4;
  const int arr = t >> 2, ac4 = (t & 3) * 4;
  float acc[8][8] = {};
  for (int kk = 0; kk < K; kk += 16) {
    #pragma unroll
    for (int h = 0; h < 2; ++h) {
      int r = arr + h * 64;
      int gr = row0 + r;
      float4 av = make_float4(0.f, 0.f, 0.f, 0.f);
      if (gr < M) av = *(const float4*)(A + (size_t)gr * K + kk + ac4);
      As[ac4 + 0][r] = av.x; As[ac4 + 1][r] = av.y;
      As[ac4 + 2][r] = av.z; As[ac4 + 3][r] = av.w;
    }
    #pragma unroll
    for (int h = 0; h < 2; ++h) {
      int idx = t + h * 256;
      int r = idx >> 5, c4 = (idx & 31) * 4;
      *(float4*)&Bs[r][c4] = *(const float4*)(B + (size_t)(kk + r) * N + col0 + c4);
    }
    __syncthreads();
    #pragma unroll
    for (int k = 0; k < 16; ++k) {
      float a[8], b[8];
      *(float4*)&a[0] = *(const float4*)&As[k][ty * 8];
      *(float4*)&a[4] = *(const float4*)&As[k][ty * 8 + 4];
      *(float4*)&b[0] = *(const float4*)&Bs[k][tx * 8];
      *(float4*)&b[4] = *(const float4*)&Bs[k][tx * 8 + 4];
      #pragma unroll
      for (int i = 0; i < 8; ++i)
        #pragma unroll
        for (int j = 0; j < 8; ++j)
          acc[i][j] = fmaf(a[i], b[j], acc[i][j]);
    }
    __syncthreads();
  }
  // epilogue: bf16 store + fused el/er (f32-exact; block's 128 cols = 2 heads)
  const int head = (col0 >> 6) + (tx >> 3);
  float alf[8], arf[8];
  #pragma unroll
  for (int j = 0; j < 8; ++j) {
    alf[j] = al[head * 64 + (tx & 7) * 8 + j];
    arf[j] = ar[head * 64 + (tx & 7) * 8 + j];
  }
  #pragma unroll
  for (int i = 0; i < 8; ++i) {
    int gr = row0 + ty * 8 + i;
    float pl = 0.f, pr = 0.f;
    #pragma unroll
    for (int j = 0; j < 8; ++j) {
      pl = fmaf(acc[i][j], alf[j], pl);
      pr = fmaf(acc[i][j], arf[j], pr);
    }
    #pragma unroll
    for (int s = 1; s <= 4; s <<= 1) { pl += __shfl_xor(pl, s); pr += __shfl_xor(pr, s); }
    if (gr < M) {
      unsigned short us[8];
      #pragma unroll
      for (int j = 0; j < 8; ++j) us[j] = f2bf(acc[i][j]);
      *(uint4*)(C + (size_t)gr * N + col0 + tx * 8) = *(const uint4*)us;
      if ((tx & 7) == 0) { el[gr * 8 + head] = pl; er[gr * 8 + head] = pr; }
    }
  }
}

// ============ GEMM2: feat2 = ELU(out1) @ W2  [50000,512]x[512,64], el2/er2 ===
__global__ __launch_bounds__(256)
void gemm2_kernel(const float* __restrict__ A, const float* __restrict__ B,
                  const float* __restrict__ al, const float* __restrict__ ar,
                  float* __restrict__ C, float* __restrict__ el, float* __restrict__ er) {
  const int M = NN, K = 512, N = 64;
  __shared__ float As[32][132];
  __shared__ float Bs[32][64];
  const int t = threadIdx.x;
  const int row0 = blockIdx.x * 128;
  const int tx = t & 15, ty = t >> 4;
  float acc[8][4] = {};
  for (int kk = 0; kk < K; kk += 32) {
    #pragma unroll
    for (int h = 0; h < 4; ++h) {
      int idx = t + h * 256;
      int r = idx >> 3, c4 = (idx & 7) * 4;
      int gr = row0 + r;
      float4 av = make_float4(0.f, 0.f, 0.f, 0.f);
      if (gr < M) av = *(const float4*)(A + (size_t)gr * K + kk + c4);
      av.x = elu(av.x); av.y = elu(av.y); av.z = elu(av.z); av.w = elu(av.w);
      As[c4 + 0][r] = av.x; As[c4 + 1][r] = av.y;
      As[c4 + 2][r] = av.z; As[c4 + 3][r] = av.w;
    }
    #pragma unroll
    for (int h = 0; h < 2; ++h) {
      int idx = t + h * 256;
      int r = idx >> 4, c4 = (idx & 15) * 4;
      *(float4*)&Bs[r][c4] = *(const float4*)(B + (size_t)(kk + r) * N + c4);
    }
    __syncthreads();
    #pragma unroll
    for (int k = 0; k < 32; ++k) {
      float a[8];
      *(float4*)&a[0] = *(const float4*)&As[k][ty * 8];
      *(float4*)&a[4] = *(const float4*)&As[k][ty * 8 + 4];
      float4 b = *(const float4*)&Bs[k][tx * 4];
      #pragma unroll
      for (int i = 0; i < 8; ++i) {
        acc[i][0] = fmaf(a[i], b.x, acc[i][0]);
        acc[i][1] = fmaf(a[i], b.y, acc[i][1]);
        acc[i][2] = fmaf(a[i], b.z, acc[i][2]);
        acc[i][3] = fmaf(a[i], b.w, acc[i][3]);
      }
    }
    __syncthreads();
  }
  float alf[4], arf[4];
  #pragma unroll
  for (int j = 0; j < 4; ++j) { alf[j] = al[tx * 4 + j]; arf[j] = ar[tx * 4 + j]; }
  #pragma unroll
  for (int i = 0; i < 8; ++i) {
    int gr = row0 + ty * 8 + i;
    float pl = 0.f, pr = 0.f;
    #pragma unroll
    for (int j = 0; j < 4; ++j) {
      pl = fmaf(acc[i][j], alf[j], pl);
      pr = fmaf(acc[i][j], arf[j], pr);
    }
    #pragma unroll
    for (int s = 1; s <= 8; s <<= 1) { pl += __shfl_xor(pl, s); pr += __shfl_xor(pr, s); }
    if (gr < M) {
      *(float4*)(C + (size_t)gr * N + tx * 4) =
          make_float4(acc[i][0], acc[i][1], acc[i][2], acc[i][3]);
      if (tx == 0) { el[gr] = pl; er[gr] = pr; }
    }
  }
}

// ===================== CSR build (by dst) ====================================
__global__ void hist_kernel(const int* __restrict__ dst, int* __restrict__ cnt, int E) {
  int e = blockIdx.x * 256 + threadIdx.x;
  if (e < E) atomicAdd(&cnt[dst[e]], 1);
}

__global__ __launch_bounds__(1024)
void scan_kernel(const int* __restrict__ cnt, int* __restrict__ rowptr, int N) {
  __shared__ int sums[1024];
  int t = threadIdx.x;
  const int CH = (N + 1023) / 1024;
  int s0 = t * CH, s1 = s0 + CH; if (s1 > N) s1 = N;
  int s = 0;
  for (int i = s0; i < s1; ++i) s += cnt[i];
  sums[t] = s;
  __syncthreads();
  for (int d = 1; d < 1024; d <<= 1) {
    int v = sums[t];
    int u = (t >= d) ? sums[t - d] : 0;
    __syncthreads();
    sums[t] = v + u;
    __syncthreads();
  }
  int run = (t == 0) ? 0 : sums[t - 1];
  for (int i = s0; i < s1; ++i) { rowptr[i] = run; run += cnt[i]; }
  if (t == 1023) rowptr[N] = sums[1023];
}

__global__ void scatter_kernel(const int* __restrict__ dst, const int* __restrict__ src,
                               const int* __restrict__ rowptr, int* __restrict__ fill,
                               int* __restrict__ srcs, int E) {
  int e = blockIdx.x * 256 + threadIdx.x;
  if (e >= E) return;
  int d = dst[e];
  int pos = atomicAdd(&fill[d], 1);
  srcs[rowptr[d] + pos] = src[e];
}

// ============ attn1: wal[i][h] = softmax per (dst-node, head) ================
__global__ __launch_bounds__(256)
void attn1_kernel(const float* __restrict__ el, const float* __restrict__ er,
                  const int* __restrict__ srcs, const int* __restrict__ rowptr,
                  float* __restrict__ wal, int N) {
  int n = blockIdx.x * 4 + (threadIdx.x >> 6);
  if (n >= N) return;
  int lane = threadIdx.x & 63;
  int j = lane >> 3, h = lane & 7;
  int p0 = rowptr[n], p1 = rowptr[n + 1];
  int deg = p1 - p0;
  if (deg == 0) return;
  float erh = er[(size_t)n * 8 + h];
  if (deg <= 64) {
    float vals[8];
    float m = -3.4e38f;
    #pragma unroll
    for (int st = 0; st < 8; ++st) {
      int i = p0 + st * 8 + j;
      float e = -3.4e38f;
      if (i < p1) e = lrelu(el[(size_t)srcs[i] * 8 + h] + erh);
      vals[st] = e;
      m = fmaxf(m, e);
    }
    m = fmaxf(m, __shfl_xor(m, 8));
    m = fmaxf(m, __shfl_xor(m, 16));
    m = fmaxf(m, __shfl_xor(m, 32));
    float z = 0.f;
    #pragma unroll
    for (int st = 0; st < 8; ++st) {
      float ev = __expf(vals[st] - m);
      vals[st] = ev;
      z += ev;
    }
    z += __shfl_xor(z, 8); z += __shfl_xor(z, 16); z += __shfl_xor(z, 32);
    float iz = 1.f / z;
    #pragma unroll
    for (int st = 0; st < 8; ++st) {
      int i = p0 + st * 8 + j;
      if (i < p1) wal[(size_t)i * 8 + h] = vals[st] * iz;
    }
  } else {
    float m = -3.4e38f;
    for (int i = p0 + j; i < p1; i += 8)
      m = fmaxf(m, lrelu(el[(size_t)srcs[i] * 8 + h] + erh));
    m = fmaxf(m, __shfl_xor(m, 8));
    m = fmaxf(m, __shfl_xor(m, 16));
    m = fmaxf(m, __shfl_xor(m, 32));
    float z = 0.f;
    for (int i = p0 + j; i < p1; i += 8)
      z += __expf(lrelu(el[(size_t)srcs[i] * 8 + h] + erh) - m);
    z += __shfl_xor(z, 8); z += __shfl_xor(z, 16); z += __shfl_xor(z, 32);
    float iz = 1.f / z;
    for (int i = p0 + j; i < p1; i += 8)
      wal[(size_t)i * 8 + h] = __expf(lrelu(el[(size_t)srcs[i] * 8 + h] + erh) - m) * iz;
  }
}

// ============ attn2: single head ============================================
__global__ __launch_bounds__(256)
void attn2_kernel(const float* __restrict__ el, const float* __restrict__ er,
                  const int* __restrict__ srcs, const int* __restrict__ rowptr,
                  float* __restrict__ wal, int N) {
  int n = blockIdx.x * 4 + (threadIdx.x >> 6);
  if (n >= N) return;
  int lane = threadIdx.x & 63;
  int p0 = rowptr[n], p1 = rowptr[n + 1];
  int deg = p1 - p0;
  if (deg == 0) return;
  float ern = er[n];
  if (deg <= 256) {
    float vals[4];
    float m = -3.4e38f;
    #pragma unroll
    for (int st = 0; st < 4; ++st) {
      int i = p0 + st * 64 + lane;
      float e = -3.4e38f;
      if (i < p1) e = lrelu(el[srcs[i]] + ern);
      vals[st] = e;
      m = fmaxf(m, e);
    }
    #pragma unroll
    for (int s = 1; s <= 32; s <<= 1) m = fmaxf(m, __shfl_xor(m, s));
    float z = 0.f;
    #pragma unroll
    for (int st = 0; st < 4; ++st) {
      float ev = __expf(vals[st] - m);
      vals[st] = ev;
      z += ev;
    }
    #pragma unroll
    for (int s = 1; s <= 32; s <<= 1) z += __shfl_xor(z, s);
    float iz = 1.f / z;
    #pragma unroll
    for (int st = 0; st < 4; ++st) {
      int i = p0 + st * 64 + lane;
      if (i < p1) wal[i] = vals[st] * iz;
    }
  } else {
    float m = -3.4e38f;
    for (int i = p0 + lane; i < p1; i += 64)
      m = fmaxf(m, lrelu(el[srcs[i]] + ern));
    #pragma unroll
    for (int s = 1; s <= 32; s <<= 1) m = fmaxf(m, __shfl_xor(m, s));
    float z = 0.f;
    for (int i = p0 + lane; i < p1; i += 64)
      z += __expf(lrelu(el[srcs[i]] + ern) - m);
    #pragma unroll
    for (int s = 1; s <= 32; s <<= 1) z += __shfl_xor(z, s);
    float iz = 1.f / z;
    for (int i = p0 + lane; i < p1; i += 64)
      wal[i] = __expf(lrelu(el[srcs[i]] + ern) - m) * iz;
  }
}

// ============ agg1: out1[n,:] = sum alpha * feat1_bf16[src,:] + b1 ===========
// single pass: lane owns 8 channels (= 16B bf16), head = lane>>3
__global__ __launch_bounds__(256)
void agg1_kernel(const unsigned short* __restrict__ feat, const float* __restrict__ wal,
                 const int* __restrict__ srcs, const int* __restrict__ rowptr,
                 const float* __restrict__ bias, float* __restrict__ out, int N) {
  int n = blockIdx.x * 4 + (threadIdx.x >> 6);
  if (n >= N) return;
  int lane = threadIdx.x & 63;
  const int myh = lane >> 3;
  int p0 = rowptr[n], p1 = rowptr[n + 1];
  float acc[8] = {};
  auto step = [&](int i) {
    int s = srcs[i];
    float w = wal[(size_t)i * 8 + myh];
    uint4 u = *(const uint4*)(feat + (size_t)s * 512 + lane * 8);
    #pragma unroll
    for (int q = 0; q < 4; ++q) {
      unsigned v = ((const unsigned*)&u)[q];
      float lo = __uint_as_float(v << 16);
      float hi = __uint_as_float(v & 0xFFFF0000u);
      acc[2 * q]     = fmaf(lo, w, acc[2 * q]);
      acc[2 * q + 1] = fmaf(hi, w, acc[2 * q + 1]);
    }
  };
  int i = p0;
  for (; i + 4 <= p1; i += 4) { step(i); step(i + 1); step(i + 2); step(i + 3); }
  for (; i < p1; ++i) step(i);
  float o[8];
  *(float4*)&o[0] = *(const float4*)(bias + lane * 8);
  *(float4*)&o[4] = *(const float4*)(bias + lane * 8 + 4);
  #pragma unroll
  for (int q = 0; q < 8; ++q) o[q] += acc[q];
  *(float4*)(out + (size_t)n * 512 + lane * 8)     = *(const float4*)&o[0];
  *(float4*)(out + (size_t)n * 512 + lane * 8 + 4) = *(const float4*)&o[4];
}

// ============ agg2: out[n] = sum alpha * feat2[src] + b2 =====================
__global__ __launch_bounds__(256)
void agg2_kernel(const float* __restrict__ feat, const float* __restrict__ wal,
                 const int* __restrict__ srcs, const int* __restrict__ rowptr,
                 const float* __restrict__ bias, float* __restrict__ out, int N) {
  int n = blockIdx.x * 4 + (threadIdx.x >> 6);
  if (n >= N) return;
  int lane = threadIdx.x & 63;
  int p0 = rowptr[n], p1 = rowptr[n + 1];
  float acc = 0.f;
  int i = p0;
  for (; i + 2 <= p1; i += 2) {
    int s0 = srcs[i], s1 = srcs[i + 1];
    float w0 = wal[i], w1 = wal[i + 1];
    acc = fmaf(feat[(size_t)s0 * 64 + lane], w0, acc);
    acc = fmaf(feat[(size_t)s1 * 64 + lane], w1, acc);
  }
  if (i < p1)
    acc = fmaf(feat[(size_t)srcs[i] * 64 + lane], wal[i], acc);
  out[(size_t)n * 64 + lane] = acc + bias[lane];
}

extern "C" void kernel_launch(void* const* d_in, const int* in_sizes, int n_in,
                              void* d_out, int out_size, void* d_ws, size_t ws_size,
                              hipStream_t stream) {
  const float* x   = (const float*)d_in[0];
  const int*   src = (const int*)d_in[1];
  const int*   dst = (const int*)d_in[2];
  const float* W1  = (const float*)d_in[3];
  const float* al1 = (const float*)d_in[4];
  const float* ar1 = (const float*)d_in[5];
  const float* b1  = (const float*)d_in[6];
  const float* W2  = (const float*)d_in[7];
  const float* al2 = (const float*)d_in[8];
  const float* ar2 = (const float*)d_in[9];
  const float* b2  = (const float*)d_in[10];
  float* out = (float*)d_out;

  char* p = (char*)d_ws;
  auto alloc = [&](size_t bytes) { void* r = (void*)p; p += (bytes + 255) & ~(size_t)255; return r; };
  unsigned short* feat1 = (unsigned short*)alloc((size_t)NN * 512 * 2);  // bf16, 51.2 MB
  float* out1  = (float*)alloc((size_t)NN * 512 * 4);
  float* el1   = (float*)alloc((size_t)NN * 8 * 4);
  float* er1   = (float*)alloc((size_t)NN * 8 * 4);
  float* wal1  = (float*)alloc((size_t)NE * 8 * 4);
  float* feat2 = (float*)alloc((size_t)NN * 64 * 4);
  float* el2   = (float*)alloc((size_t)NN * 4);
  float* er2   = (float*)alloc((size_t)NN * 4);
  float* wal2  = (float*)alloc((size_t)NE * 4);
  int* rowptr  = (int*)alloc((size_t)(NN + 1) * 4);
  int* srcs    = (int*)alloc((size_t)NE * 4);
  int* cnt     = (int*)alloc((size_t)NN * 4);
  int* fill    = (int*)alloc((size_t)NN * 4);

  hipMemsetAsync(cnt, 0, (size_t)NN * 4, stream);
  hipMemsetAsync(fill, 0, (size_t)NN * 4, stream);

  // CSR build (shared by both layers)
  hist_kernel<<<(NE + 255) / 256, 256, 0, stream>>>(dst, cnt, NE);
  scan_kernel<<<1, 1024, 0, stream>>>(cnt, rowptr, NN);
  scatter_kernel<<<(NE + 255) / 256, 256, 0, stream>>>(dst, src, rowptr, fill, srcs, NE);

  // layer 1
  gemm1_kernel<<<dim3(391, 4), 256, 0, stream>>>(x, W1, al1, ar1, feat1, el1, er1);
  attn1_kernel<<<(NN + 3) / 4, 256, 0, stream>>>(el1, er1, srcs, rowptr, wal1, NN);
  agg1_kernel<<<(NN + 3) / 4, 256, 0, stream>>>(feat1, wal1, srcs, rowptr, b1, out1, NN);

  // layer 2
  gemm2_kernel<<<dim3(391, 1), 256, 0, stream>>>(out1, W2, al2, ar2, feat2, el2, er2);
  attn2_kernel<<<(NN + 3) / 4, 256, 0, stream>>>(el2, er2, srcs, rowptr, wal2, NN);
  agg2_kernel<<<(NN + 3) / 4, 256, 0, stream>>>(feat2, wal2, srcs, rowptr, b2, out, NN);
}

// Round 4
// 519.538 us; speedup vs baseline: 1.8535x; 1.0380x over previous
//
#include <hip/hip_runtime.h>
#include <cstdint>

// GAT 2-layer: N=50000 nodes, E=800000 edges
// L1: 128 -> 8 heads x 64 (512) [feat1 bf16], ELU, L2: 512 -> 1 x 64
// attn softmax fused into aggregation kernels; out1 stored bf16 ELU-applied.
#define NN 50000
#define NE 800000

__device__ __forceinline__ float lrelu(float x) { return x > 0.f ? x : 0.2f * x; }
__device__ __forceinline__ float elu(float x) { return x > 0.f ? x : __expf(x) - 1.f; }

__device__ __forceinline__ unsigned short f2bf(float f) {
  unsigned u = __float_as_uint(f);
  unsigned r = (u + 0x7FFFu + ((u >> 16) & 1u)) >> 16;   // RNE
  return (unsigned short)r;
}

// ============ GEMM1: feat1(bf16) = x @ W1  [50000,128]x[128,512], + el1/er1 ==
// BM=128 BN=128 BK=16, 256 threads, 8x8 micro-tile; thread cols split
// {tx*4..+3, 64+tx*4..+3} so B-fragment LDS reads are 2-way (free) not 4-way.
__global__ __launch_bounds__(256)
void gemm1_kernel(const float* __restrict__ A, const float* __restrict__ B,
                  const float* __restrict__ al, const float* __restrict__ ar,
                  unsigned short* __restrict__ C, float* __restrict__ el,
                  float* __restrict__ er) {
  const int M = NN, K = 128, N = 512;
  __shared__ float As[16][132];
  __shared__ float Bs[16][128];
  const int t = threadIdx.x;
  const int row0 = blockIdx.x * 128, col0 = blockIdx.y * 128;
  const int tx = t & 15, ty = t >> 4;
  const int arr = t >> 2, ac4 = (t & 3) * 4;
  float acc[8][8] = {};   // [row i][j: 0-3 -> col tx*4+j, 4-7 -> col 64+tx*4+j-4]
  for (int kk = 0; kk < K; kk += 16) {
    #pragma unroll
    for (int h = 0; h < 2; ++h) {
      int r = arr + h * 64;
      int gr = row0 + r;
      float4 av = make_float4(0.f, 0.f, 0.f, 0.f);
      if (gr < M) av = *(const float4*)(A + (size_t)gr * K + kk + ac4);
      As[ac4 + 0][r] = av.x; As[ac4 + 1][r] = av.y;
      As[ac4 + 2][r] = av.z; As[ac4 + 3][r] = av.w;
    }
    #pragma unroll
    for (int h = 0; h < 2; ++h) {
      int idx = t + h * 256;
      int r = idx >> 5, c4 = (idx & 31) * 4;
      *(float4*)&Bs[r][c4] = *(const float4*)(B + (size_t)(kk + r) * N + col0 + c4);
    }
    __syncthreads();
    #pragma unroll
    for (int k = 0; k < 16; ++k) {
      float a[8], b[8];
      *(float4*)&a[0] = *(const float4*)&As[k][ty * 8];
      *(float4*)&a[4] = *(const float4*)&As[k][ty * 8 + 4];
      *(float4*)&b[0] = *(const float4*)&Bs[k][tx * 4];        // banks tx*4%32: 2-way
      *(float4*)&b[4] = *(const float4*)&Bs[k][64 + tx * 4];
      #pragma unroll
      for (int i = 0; i < 8; ++i)
        #pragma unroll
        for (int j = 0; j < 8; ++j)
          acc[i][j] = fmaf(a[i], b[j], acc[i][j]);
    }
    __syncthreads();
  }
  // epilogue: bf16 store + fused el/er. Block's cols = heads hA, hA+1.
  const int hA = col0 >> 6;
  float alfA[4], arfA[4], alfB[4], arfB[4];
  #pragma unroll
  for (int j = 0; j < 4; ++j) {
    alfA[j] = al[hA * 64 + tx * 4 + j];
    arfA[j] = ar[hA * 64 + tx * 4 + j];
    alfB[j] = al[(hA + 1) * 64 + tx * 4 + j];
    arfB[j] = ar[(hA + 1) * 64 + tx * 4 + j];
  }
  #pragma unroll
  for (int i = 0; i < 8; ++i) {
    int gr = row0 + ty * 8 + i;
    float plA = 0.f, prA = 0.f, plB = 0.f, prB = 0.f;
    #pragma unroll
    for (int j = 0; j < 4; ++j) {
      plA = fmaf(acc[i][j], alfA[j], plA);
      prA = fmaf(acc[i][j], arfA[j], prA);
      plB = fmaf(acc[i][j + 4], alfB[j], plB);
      prB = fmaf(acc[i][j + 4], arfB[j], prB);
    }
    #pragma unroll
    for (int s = 1; s <= 8; s <<= 1) {
      plA += __shfl_xor(plA, s); prA += __shfl_xor(prA, s);
      plB += __shfl_xor(plB, s); prB += __shfl_xor(prB, s);
    }
    if (gr < M) {
      unsigned short us[8];
      #pragma unroll
      for (int j = 0; j < 8; ++j) us[j] = f2bf(acc[i][j]);
      *(uint2*)(C + (size_t)gr * N + col0 + tx * 4) = *(const uint2*)&us[0];
      *(uint2*)(C + (size_t)gr * N + col0 + 64 + tx * 4) = *(const uint2*)&us[4];
      if (tx == 0) {
        el[gr * 8 + hA] = plA;     er[gr * 8 + hA] = prA;
        el[gr * 8 + hA + 1] = plB; er[gr * 8 + hA + 1] = prB;
      }
    }
  }
}

// ===== GEMM2: feat2 = out1e(bf16, ELU applied) @ W2 [50000,512]x[512,64] =====
__global__ __launch_bounds__(256)
void gemm2_kernel(const unsigned short* __restrict__ A, const float* __restrict__ B,
                  const float* __restrict__ al, const float* __restrict__ ar,
                  float* __restrict__ C, float* __restrict__ el, float* __restrict__ er) {
  const int M = NN, K = 512, N = 64;
  __shared__ float As[32][132];
  __shared__ float Bs[32][64];
  const int t = threadIdx.x;
  const int row0 = blockIdx.x * 128;
  const int tx = t & 15, ty = t >> 4;
  float acc[8][4] = {};
  for (int kk = 0; kk < K; kk += 32) {
    #pragma unroll
    for (int h = 0; h < 4; ++h) {
      int idx = t + h * 256;
      int r = idx >> 3, c4 = (idx & 7) * 4;
      int gr = row0 + r;
      uint2 u = make_uint2(0u, 0u);
      if (gr < M) u = *(const uint2*)(A + (size_t)gr * K + kk + c4);
      As[c4 + 0][r] = __uint_as_float(u.x << 16);
      As[c4 + 1][r] = __uint_as_float(u.x & 0xFFFF0000u);
      As[c4 + 2][r] = __uint_as_float(u.y << 16);
      As[c4 + 3][r] = __uint_as_float(u.y & 0xFFFF0000u);
    }
    #pragma unroll
    for (int h = 0; h < 2; ++h) {
      int idx = t + h * 256;
      int r = idx >> 4, c4 = (idx & 15) * 4;
      *(float4*)&Bs[r][c4] = *(const float4*)(B + (size_t)(kk + r) * N + c4);
    }
    __syncthreads();
    #pragma unroll
    for (int k = 0; k < 32; ++k) {
      float a[8];
      *(float4*)&a[0] = *(const float4*)&As[k][ty * 8];
      *(float4*)&a[4] = *(const float4*)&As[k][ty * 8 + 4];
      float4 b = *(const float4*)&Bs[k][tx * 4];
      #pragma unroll
      for (int i = 0; i < 8; ++i) {
        acc[i][0] = fmaf(a[i], b.x, acc[i][0]);
        acc[i][1] = fmaf(a[i], b.y, acc[i][1]);
        acc[i][2] = fmaf(a[i], b.z, acc[i][2]);
        acc[i][3] = fmaf(a[i], b.w, acc[i][3]);
      }
    }
    __syncthreads();
  }
  float alf[4], arf[4];
  #pragma unroll
  for (int j = 0; j < 4; ++j) { alf[j] = al[tx * 4 + j]; arf[j] = ar[tx * 4 + j]; }
  #pragma unroll
  for (int i = 0; i < 8; ++i) {
    int gr = row0 + ty * 8 + i;
    float pl = 0.f, pr = 0.f;
    #pragma unroll
    for (int j = 0; j < 4; ++j) {
      pl = fmaf(acc[i][j], alf[j], pl);
      pr = fmaf(acc[i][j], arf[j], pr);
    }
    #pragma unroll
    for (int s = 1; s <= 8; s <<= 1) { pl += __shfl_xor(pl, s); pr += __shfl_xor(pr, s); }
    if (gr < M) {
      *(float4*)(C + (size_t)gr * N + tx * 4) =
          make_float4(acc[i][0], acc[i][1], acc[i][2], acc[i][3]);
      if (tx == 0) { el[gr] = pl; er[gr] = pr; }
    }
  }
}

// ===================== CSR build (by dst) ====================================
__global__ void hist_kernel(const int* __restrict__ dst, int* __restrict__ cnt, int E) {
  int e = blockIdx.x * 256 + threadIdx.x;
  if (e < E) atomicAdd(&cnt[dst[e]], 1);
}

__global__ __launch_bounds__(1024)
void scan_kernel(const int* __restrict__ cnt, int* __restrict__ rowptr, int N) {
  __shared__ int sums[1024];
  int t = threadIdx.x;
  const int CH = (N + 1023) / 1024;
  int s0 = t * CH, s1 = s0 + CH; if (s1 > N) s1 = N;
  int s = 0;
  for (int i = s0; i < s1; ++i) s += cnt[i];
  sums[t] = s;
  __syncthreads();
  for (int d = 1; d < 1024; d <<= 1) {
    int v = sums[t];
    int u = (t >= d) ? sums[t - d] : 0;
    __syncthreads();
    sums[t] = v + u;
    __syncthreads();
  }
  int run = (t == 0) ? 0 : sums[t - 1];
  for (int i = s0; i < s1; ++i) { rowptr[i] = run; run += cnt[i]; }
  if (t == 1023) rowptr[N] = sums[1023];
}

__global__ void scatter_kernel(const int* __restrict__ dst, const int* __restrict__ src,
                               const int* __restrict__ rowptr, int* __restrict__ fill,
                               int* __restrict__ srcs, int E) {
  int e = blockIdx.x * 256 + threadIdx.x;
  if (e >= E) return;
  int d = dst[e];
  int pos = atomicAdd(&fill[d], 1);
  srcs[rowptr[d] + pos] = src[e];
}

// ==== agg1f: fused edge-softmax + aggregate + bias + ELU + bf16 store ========
// wave per node; lane: head = lane>>3 (8 lanes/head), j = lane&7 edge-stride.
// out1e[n,c] = bf16(elu(sum_i alpha_i * feat1[src_i, c] + b1[c]))
__global__ __launch_bounds__(256)
void agg1f_kernel(const unsigned short* __restrict__ feat,
                  const float* __restrict__ el, const float* __restrict__ er,
                  const int* __restrict__ srcs, const int* __restrict__ rowptr,
                  const float* __restrict__ bias, unsigned short* __restrict__ out,
                  int N) {
  int n = blockIdx.x * 4 + (threadIdx.x >> 6);
  if (n >= N) return;
  int lane = threadIdx.x & 63;
  const int myh = lane >> 3, j = lane & 7;
  int p0 = rowptr[n], p1 = rowptr[n + 1];
  float erh = er[(size_t)n * 8 + myh];
  // --- softmax stats per (n, head): 8 lanes stride the edge list ---
  float m = -3.4e38f;
  for (int i = p0 + j; i < p1; i += 8)
    m = fmaxf(m, lrelu(el[(size_t)srcs[i] * 8 + myh] + erh));
  m = fmaxf(m, __shfl_xor(m, 1));
  m = fmaxf(m, __shfl_xor(m, 2));
  m = fmaxf(m, __shfl_xor(m, 4));
  float z = 0.f;
  for (int i = p0 + j; i < p1; i += 8)
    z += __expf(lrelu(el[(size_t)srcs[i] * 8 + myh] + erh) - m);
  z += __shfl_xor(z, 1); z += __shfl_xor(z, 2); z += __shfl_xor(z, 4);
  float iz = (p1 > p0) ? 1.f / z : 0.f;
  // --- weighted aggregation: all 64 lanes walk all edges ---
  float acc[8] = {};
  auto step = [&](int i) {
    int s = srcs[i];
    float w = __expf(lrelu(el[(size_t)s * 8 + myh] + erh) - m) * iz;
    uint4 u = *(const uint4*)(feat + (size_t)s * 512 + lane * 8);
    #pragma unroll
    for (int q = 0; q < 4; ++q) {
      unsigned v = ((const unsigned*)&u)[q];
      float lo = __uint_as_float(v << 16);
      float hi = __uint_as_float(v & 0xFFFF0000u);
      acc[2 * q]     = fmaf(lo, w, acc[2 * q]);
      acc[2 * q + 1] = fmaf(hi, w, acc[2 * q + 1]);
    }
  };
  int i = p0;
  for (; i + 2 <= p1; i += 2) { step(i); step(i + 1); }
  if (i < p1) step(i);
  // --- bias + ELU + bf16 pack ---
  float bv[8];
  *(float4*)&bv[0] = *(const float4*)(bias + lane * 8);
  *(float4*)&bv[4] = *(const float4*)(bias + lane * 8 + 4);
  unsigned short us[8];
  #pragma unroll
  for (int q = 0; q < 8; ++q) us[q] = f2bf(elu(acc[q] + bv[q]));
  *(uint4*)(out + (size_t)n * 512 + lane * 8) = *(const uint4*)us;
}

// ==== agg2f: fused edge-softmax + aggregate + bias (single head) =============
__global__ __launch_bounds__(256)
void agg2f_kernel(const float* __restrict__ feat,
                  const float* __restrict__ el, const float* __restrict__ er,
                  const int* __restrict__ srcs, const int* __restrict__ rowptr,
                  const float* __restrict__ bias, float* __restrict__ out, int N) {
  int n = blockIdx.x * 4 + (threadIdx.x >> 6);
  if (n >= N) return;
  int lane = threadIdx.x & 63;
  int p0 = rowptr[n], p1 = rowptr[n + 1];
  float ern = er[n];
  float m = -3.4e38f;
  for (int i = p0 + lane; i < p1; i += 64)
    m = fmaxf(m, lrelu(el[srcs[i]] + ern));
  #pragma unroll
  for (int s = 1; s <= 32; s <<= 1) m = fmaxf(m, __shfl_xor(m, s));
  float z = 0.f;
  for (int i = p0 + lane; i < p1; i += 64)
    z += __expf(lrelu(el[srcs[i]] + ern) - m);
  #pragma unroll
  for (int s = 1; s <= 32; s <<= 1) z += __shfl_xor(z, s);
  float iz = (p1 > p0) ? 1.f / z : 0.f;
  float acc = 0.f;
  int i = p0;
  for (; i + 2 <= p1; i += 2) {
    int s0 = srcs[i], s1 = srcs[i + 1];
    float w0 = __expf(lrelu(el[s0] + ern) - m) * iz;
    float w1 = __expf(lrelu(el[s1] + ern) - m) * iz;
    acc = fmaf(feat[(size_t)s0 * 64 + lane], w0, acc);
    acc = fmaf(feat[(size_t)s1 * 64 + lane], w1, acc);
  }
  if (i < p1) {
    int s0 = srcs[i];
    float w0 = __expf(lrelu(el[s0] + ern) - m) * iz;
    acc = fmaf(feat[(size_t)s0 * 64 + lane], w0, acc);
  }
  out[(size_t)n * 64 + lane] = acc + bias[lane];
}

extern "C" void kernel_launch(void* const* d_in, const int* in_sizes, int n_in,
                              void* d_out, int out_size, void* d_ws, size_t ws_size,
                              hipStream_t stream) {
  const float* x   = (const float*)d_in[0];
  const int*   src = (const int*)d_in[1];
  const int*   dst = (const int*)d_in[2];
  const float* W1  = (const float*)d_in[3];
  const float* al1 = (const float*)d_in[4];
  const float* ar1 = (const float*)d_in[5];
  const float* b1  = (const float*)d_in[6];
  const float* W2  = (const float*)d_in[7];
  const float* al2 = (const float*)d_in[8];
  const float* ar2 = (const float*)d_in[9];
  const float* b2  = (const float*)d_in[10];
  float* out = (float*)d_out;

  char* p = (char*)d_ws;
  auto alloc = [&](size_t bytes) { void* r = (void*)p; p += (bytes + 255) & ~(size_t)255; return r; };
  unsigned short* feat1 = (unsigned short*)alloc((size_t)NN * 512 * 2);  // bf16
  unsigned short* out1e = (unsigned short*)alloc((size_t)NN * 512 * 2);  // bf16, ELU applied
  float* el1   = (float*)alloc((size_t)NN * 8 * 4);
  float* er1   = (float*)alloc((size_t)NN * 8 * 4);
  float* feat2 = (float*)alloc((size_t)NN * 64 * 4);
  float* el2   = (float*)alloc((size_t)NN * 4);
  float* er2   = (float*)alloc((size_t)NN * 4);
  int* rowptr  = (int*)alloc((size_t)(NN + 1) * 4);
  int* srcs    = (int*)alloc((size_t)NE * 4);
  int* cnt     = (int*)alloc((size_t)NN * 4);
  int* fill    = (int*)alloc((size_t)NN * 4);

  hipMemsetAsync(cnt, 0, (size_t)NN * 4, stream);
  hipMemsetAsync(fill, 0, (size_t)NN * 4, stream);

  // CSR build (shared by both layers)
  hist_kernel<<<(NE + 255) / 256, 256, 0, stream>>>(dst, cnt, NE);
  scan_kernel<<<1, 1024, 0, stream>>>(cnt, rowptr, NN);
  scatter_kernel<<<(NE + 255) / 256, 256, 0, stream>>>(dst, src, rowptr, fill, srcs, NE);

  // layer 1
  gemm1_kernel<<<dim3(391, 4), 256, 0, stream>>>(x, W1, al1, ar1, feat1, el1, er1);
  agg1f_kernel<<<(NN + 3) / 4, 256, 0, stream>>>(feat1, el1, er1, srcs, rowptr, b1, out1e, NN);

  // layer 2
  gemm2_kernel<<<dim3(391, 1), 256, 0, stream>>>(out1e, W2, al2, ar2, feat2, el2, er2);
  agg2f_kernel<<<(NN + 3) / 4, 256, 0, stream>>>(feat2, el2, er2, srcs, rowptr, b2, out, NN);
}

// Round 6
// 393.055 us; speedup vs baseline: 2.4499x; 1.3218x over previous
//
#include <hip/hip_runtime.h>
#include <cstdint>

// GAT 2-layer: N=50000, E=800000. L1: 128 -> 8x64 (bf16 feat1), ELU, L2: 512 -> 64.
// MFMA bf16 GEMMs (f32 accum), fused softmax-agg with LDS weight staging.
#define NN 50000
#define NE 800000

typedef short bf16x8 __attribute__((ext_vector_type(8)));
typedef float f32x4 __attribute__((ext_vector_type(4)));

__device__ __forceinline__ float lrelu(float x) { return x > 0.f ? x : 0.2f * x; }
__device__ __forceinline__ float elu(float x) { return x > 0.f ? x : __expf(x) - 1.f; }
__device__ __forceinline__ unsigned short f2bf(float f) {
  unsigned u = __float_as_uint(f);
  unsigned r = (u + 0x7FFFu + ((u >> 16) & 1u)) >> 16;   // RNE
  return (unsigned short)r;
}

// ===================== prep: dtype converts / transposes =====================
__global__ __launch_bounds__(256)
void cvt_x_kernel(const float* __restrict__ in, unsigned short* __restrict__ outb) {
  int idx = blockIdx.x * 256 + threadIdx.x;      // 8 elems each
  if (idx >= NN * 128 / 8) return;
  float4 a = *(const float4*)(in + (size_t)idx * 8);
  float4 b = *(const float4*)(in + (size_t)idx * 8 + 4);
  unsigned short us[8] = { f2bf(a.x), f2bf(a.y), f2bf(a.z), f2bf(a.w),
                           f2bf(b.x), f2bf(b.y), f2bf(b.z), f2bf(b.w) };
  *(uint4*)(outb + (size_t)idx * 8) = *(const uint4*)us;
}

// W [K][N] f32 -> WT [N][K] bf16 (reads coalesced)
template<int K, int N>
__global__ __launch_bounds__(256)
void cvt_wt_kernel(const float* __restrict__ w, unsigned short* __restrict__ wt) {
  int idx = blockIdx.x * 256 + threadIdx.x;
  if (idx >= K * N) return;
  int k = idx / N, c = idx % N;
  wt[(size_t)c * K + k] = f2bf(w[idx]);
}

// ====== GEMM1 (MFMA): feat1(bf16) = xb @ W1T^T, fused el1/er1 ================
// BM=128 BN=128 BK=32, 4 waves (2x2), wave tile 64x64 = 4x4 fragments.
__global__ __launch_bounds__(256)
void gemm1_mfma(const unsigned short* __restrict__ xb,    // [NN][128] bf16
                const unsigned short* __restrict__ w1t,   // [512][128] bf16
                const float* __restrict__ al, const float* __restrict__ ar,
                unsigned short* __restrict__ feat,        // [NN][512] bf16
                float* __restrict__ el, float* __restrict__ er) {
  __shared__ unsigned short As[128][40];   // pad: stride 80B -> 2-way (free)
  __shared__ unsigned short Bs[128][40];
  const int t = threadIdx.x, lane = t & 63, wid = t >> 6;
  const int wr = wid >> 1, wc = wid & 1;
  const int row0 = blockIdx.x * 128, col0 = blockIdx.y * 128;
  const int l15 = lane & 15, kg = lane >> 4;
  f32x4 acc[4][4] = {};
  for (int kk = 0; kk < 128; kk += 32) {
    // stage 128 rows x 32 shorts for both A and B: 512 uint4 chunks each,
    // 2 per thread (FIX: previous version left shorts 8-15,24-31 unwritten)
    #pragma unroll
    for (int it = 0; it < 2; ++it) {
      int c = t + it * 256;
      int r = c >> 2, kc = (c & 3) * 8;
      uint4 va = make_uint4(0, 0, 0, 0);
      if (row0 + r < NN) va = *(const uint4*)(xb + (size_t)(row0 + r) * 128 + kk + kc);
      *(uint4*)&As[r][kc] = va;
      *(uint4*)&Bs[r][kc] = *(const uint4*)(w1t + (size_t)(col0 + r) * 128 + kk + kc);
    }
    __syncthreads();
    bf16x8 af[4], bfr[4];
    #pragma unroll
    for (int f = 0; f < 4; ++f) {
      af[f]  = *(const bf16x8*)&As[wr * 64 + f * 16 + l15][kg * 8];
      bfr[f] = *(const bf16x8*)&Bs[wc * 64 + f * 16 + l15][kg * 8];
    }
    #pragma unroll
    for (int fi = 0; fi < 4; ++fi)
      #pragma unroll
      for (int fj = 0; fj < 4; ++fj)
        acc[fi][fj] = __builtin_amdgcn_mfma_f32_16x16x32_bf16(af[fi], bfr[fj], acc[fi][fj], 0, 0, 0);
    __syncthreads();
  }
  // epilogue: wave covers exactly head = blockIdx.y*2 + wc
  const int head = blockIdx.y * 2 + wc;
  float alf[4], arf[4];
  #pragma unroll
  for (int fj = 0; fj < 4; ++fj) {
    alf[fj] = al[head * 64 + fj * 16 + l15];
    arf[fj] = ar[head * 64 + fj * 16 + l15];
  }
  #pragma unroll
  for (int fi = 0; fi < 4; ++fi) {
    float pl[4] = {}, pr[4] = {};
    #pragma unroll
    for (int fj = 0; fj < 4; ++fj)
      #pragma unroll
      for (int r = 0; r < 4; ++r) {
        pl[r] = fmaf(acc[fi][fj][r], alf[fj], pl[r]);
        pr[r] = fmaf(acc[fi][fj][r], arf[fj], pr[r]);
      }
    const int rbase = row0 + wr * 64 + fi * 16 + kg * 4;
    #pragma unroll
    for (int r = 0; r < 4; ++r) {
      int row = rbase + r;
      if (row < NN) {
        size_t o = (size_t)row * 512 + col0 + wc * 64 + l15;
        #pragma unroll
        for (int fj = 0; fj < 4; ++fj) feat[o + fj * 16] = f2bf(acc[fi][fj][r]);
      }
    }
    #pragma unroll
    for (int s = 1; s <= 8; s <<= 1)
      #pragma unroll
      for (int r = 0; r < 4; ++r) {
        pl[r] += __shfl_xor(pl[r], s);
        pr[r] += __shfl_xor(pr[r], s);
      }
    if (l15 == 0) {
      #pragma unroll
      for (int r = 0; r < 4; ++r) {
        int row = rbase + r;
        if (row < NN) {
          el[(size_t)row * 8 + head] = pl[r];
          er[(size_t)row * 8 + head] = pr[r];
        }
      }
    }
  }
}

// ====== GEMM2 (MFMA): feat2(f32) = out1e @ W2T^T, fused el2/er2 ==============
// BM=128 BN=64 BK=64, 4 waves stacked in M, wave tile 32x64 = 2x4 fragments.
__global__ __launch_bounds__(256)
void gemm2_mfma(const unsigned short* __restrict__ A,     // out1e [NN][512] bf16
                const unsigned short* __restrict__ w2t,   // [64][512] bf16
                const float* __restrict__ al, const float* __restrict__ ar,
                float* __restrict__ C,                    // feat2 [NN][64] f32
                float* __restrict__ el, float* __restrict__ er) {
  __shared__ unsigned short As[128][72];   // stride 144B -> 2-way
  __shared__ unsigned short Bs[64][72];
  const int t = threadIdx.x, lane = t & 63, wid = t >> 6;
  const int row0 = blockIdx.x * 128;
  const int l15 = lane & 15, kg = lane >> 4;
  f32x4 acc[2][4] = {};
  for (int kk = 0; kk < 512; kk += 64) {
    #pragma unroll
    for (int it = 0; it < 4; ++it) {
      int c = t + it * 256;                 // 1024 chunks of 16B
      int r = c >> 3, kc = (c & 7) * 8;
      uint4 v = make_uint4(0, 0, 0, 0);
      if (row0 + r < NN) v = *(const uint4*)(A + (size_t)(row0 + r) * 512 + kk + kc);
      *(uint4*)&As[r][kc] = v;
    }
    #pragma unroll
    for (int it = 0; it < 2; ++it) {
      int c = t + it * 256;                 // 512 chunks
      int r = c >> 3, kc = (c & 7) * 8;
      *(uint4*)&Bs[r][kc] = *(const uint4*)(w2t + (size_t)r * 512 + kk + kc);
    }
    __syncthreads();
    #pragma unroll
    for (int ks = 0; ks < 2; ++ks) {
      bf16x8 af[2], bfr[4];
      #pragma unroll
      for (int fi = 0; fi < 2; ++fi)
        af[fi] = *(const bf16x8*)&As[wid * 32 + fi * 16 + l15][ks * 32 + kg * 8];
      #pragma unroll
      for (int fj = 0; fj < 4; ++fj)
        bfr[fj] = *(const bf16x8*)&Bs[fj * 16 + l15][ks * 32 + kg * 8];
      #pragma unroll
      for (int fi = 0; fi < 2; ++fi)
        #pragma unroll
        for (int fj = 0; fj < 4; ++fj)
          acc[fi][fj] = __builtin_amdgcn_mfma_f32_16x16x32_bf16(af[fi], bfr[fj], acc[fi][fj], 0, 0, 0);
    }
    __syncthreads();
  }
  float alf[4], arf[4];
  #pragma unroll
  for (int fj = 0; fj < 4; ++fj) { alf[fj] = al[fj * 16 + l15]; arf[fj] = ar[fj * 16 + l15]; }
  #pragma unroll
  for (int fi = 0; fi < 2; ++fi) {
    float pl[4] = {}, pr[4] = {};
    #pragma unroll
    for (int fj = 0; fj < 4; ++fj)
      #pragma unroll
      for (int r = 0; r < 4; ++r) {
        pl[r] = fmaf(acc[fi][fj][r], alf[fj], pl[r]);
        pr[r] = fmaf(acc[fi][fj][r], arf[fj], pr[r]);
      }
    const int rbase = row0 + wid * 32 + fi * 16 + kg * 4;
    #pragma unroll
    for (int r = 0; r < 4; ++r) {
      int row = rbase + r;
      if (row < NN) {
        #pragma unroll
        for (int fj = 0; fj < 4; ++fj) C[(size_t)row * 64 + fj * 16 + l15] = acc[fi][fj][r];
      }
    }
    #pragma unroll
    for (int s = 1; s <= 8; s <<= 1)
      #pragma unroll
      for (int r = 0; r < 4; ++r) {
        pl[r] += __shfl_xor(pl[r], s);
        pr[r] += __shfl_xor(pr[r], s);
      }
    if (l15 == 0) {
      #pragma unroll
      for (int r = 0; r < 4; ++r) {
        int row = rbase + r;
        if (row < NN) { el[row] = pl[r]; er[row] = pr[r]; }
      }
    }
  }
}

// ===================== CSR build (by dst) ====================================
__global__ void hist_kernel(const int* __restrict__ dst, int* __restrict__ cnt, int E) {
  int e = blockIdx.x * 256 + threadIdx.x;
  if (e < E) atomicAdd(&cnt[dst[e]], 1);
}

__global__ __launch_bounds__(1024)
void scan_kernel(const int* __restrict__ cnt, int* __restrict__ rowptr, int N) {
  __shared__ int sums[1024];
  int t = threadIdx.x;
  const int CH = (N + 1023) / 1024;
  int s0 = t * CH, s1 = s0 + CH; if (s1 > N) s1 = N;
  int s = 0;
  for (int i = s0; i < s1; ++i) s += cnt[i];
  sums[t] = s;
  __syncthreads();
  for (int d = 1; d < 1024; d <<= 1) {
    int v = sums[t];
    int u = (t >= d) ? sums[t - d] : 0;
    __syncthreads();
    sums[t] = v + u;
    __syncthreads();
  }
  int run = (t == 0) ? 0 : sums[t - 1];
  for (int i = s0; i < s1; ++i) { rowptr[i] = run; run += cnt[i]; }
  if (t == 1023) rowptr[N] = sums[1023];
}

__global__ void scatter_kernel(const int* __restrict__ dst, const int* __restrict__ src,
                               const int* __restrict__ rowptr, int* __restrict__ fill,
                               int* __restrict__ srcs, int E) {
  int e = blockIdx.x * 256 + threadIdx.x;
  if (e >= E) return;
  int d = dst[e];
  int pos = atomicAdd(&fill[d], 1);
  srcs[rowptr[d] + pos] = src[e];
}

// ==== agg1f: fused softmax+aggregate, LDS-staged weights =====================
// wave/node; lane: head = lane>>3, slot-stride j = lane&7; channels lane*8..+8
__global__ __launch_bounds__(256)
void agg1f_kernel(const unsigned short* __restrict__ feat,
                  const float* __restrict__ el, const float* __restrict__ er,
                  const int* __restrict__ srcs, const int* __restrict__ rowptr,
                  const float* __restrict__ bias, unsigned short* __restrict__ out,
                  int N) {
  __shared__ float wlds[4][512];          // 64 slots x 8 heads per wave
  int wv = threadIdx.x >> 6;
  int n = blockIdx.x * 4 + wv;
  if (n >= N) return;
  int lane = threadIdx.x & 63;
  const int myh = lane >> 3, j = lane & 7;
  int p0 = rowptr[n], p1 = rowptr[n + 1];
  int deg = p1 - p0;
  float erh = er[(size_t)n * 8 + myh];
  float* wl = wlds[wv];
  float acc[8] = {};
  auto stepw = [&](int i, float w) {
    int s = srcs[i];
    uint4 u = *(const uint4*)(feat + (size_t)s * 512 + lane * 8);
    #pragma unroll
    for (int q = 0; q < 4; ++q) {
      unsigned v = ((const unsigned*)&u)[q];
      acc[2 * q]     = fmaf(__uint_as_float(v << 16), w, acc[2 * q]);
      acc[2 * q + 1] = fmaf(__uint_as_float(v & 0xFFFF0000u), w, acc[2 * q + 1]);
    }
  };
  if (deg <= 64) {
    float ev[8];
    float m = -3.4e38f;
    #pragma unroll
    for (int st = 0; st < 8; ++st) {
      int i = p0 + st * 8 + j;
      float e = -3.4e38f;
      if (i < p1) e = lrelu(el[(size_t)srcs[i] * 8 + myh] + erh);
      ev[st] = e; m = fmaxf(m, e);
    }
    m = fmaxf(m, __shfl_xor(m, 1));
    m = fmaxf(m, __shfl_xor(m, 2));
    m = fmaxf(m, __shfl_xor(m, 4));
    float z = 0.f;
    #pragma unroll
    for (int st = 0; st < 8; ++st) { ev[st] = __expf(ev[st] - m); z += ev[st]; }
    z += __shfl_xor(z, 1); z += __shfl_xor(z, 2); z += __shfl_xor(z, 4);
    float iz = (deg > 0) ? 1.f / z : 0.f;
    #pragma unroll
    for (int st = 0; st < 8; ++st)
      wl[(st * 8 + j) * 8 + myh] = ev[st] * iz;      // banks: perm of 0..63 -> 2-way
    asm volatile("s_waitcnt lgkmcnt(0)" ::: "memory");
    int i = p0, sl = 0;
    for (; i + 4 <= p1; i += 4, sl += 4) {
      float w0 = wl[(sl + 0) * 8 + myh], w1 = wl[(sl + 1) * 8 + myh];
      float w2 = wl[(sl + 2) * 8 + myh], w3 = wl[(sl + 3) * 8 + myh];
      stepw(i, w0); stepw(i + 1, w1); stepw(i + 2, w2); stepw(i + 3, w3);
    }
    for (; i < p1; ++i, ++sl) stepw(i, wl[sl * 8 + myh]);
  } else {
    float m = -3.4e38f;
    for (int i = p0 + j; i < p1; i += 8)
      m = fmaxf(m, lrelu(el[(size_t)srcs[i] * 8 + myh] + erh));
    m = fmaxf(m, __shfl_xor(m, 1));
    m = fmaxf(m, __shfl_xor(m, 2));
    m = fmaxf(m, __shfl_xor(m, 4));
    float z = 0.f;
    for (int i = p0 + j; i < p1; i += 8)
      z += __expf(lrelu(el[(size_t)srcs[i] * 8 + myh] + erh) - m);
    z += __shfl_xor(z, 1); z += __shfl_xor(z, 2); z += __shfl_xor(z, 4);
    float iz = 1.f / z;
    for (int i = p0; i < p1; ++i) {
      int s = srcs[i];
      float w = __expf(lrelu(el[(size_t)s * 8 + myh] + erh) - m) * iz;
      stepw(i, w);
    }
  }
  float bv[8];
  *(float4*)&bv[0] = *(const float4*)(bias + lane * 8);
  *(float4*)&bv[4] = *(const float4*)(bias + lane * 8 + 4);
  unsigned short us[8];
  #pragma unroll
  for (int q = 0; q < 8; ++q) us[q] = f2bf(elu(acc[q] + bv[q]));
  *(uint4*)(out + (size_t)n * 512 + lane * 8) = *(const uint4*)us;
}

// ==== agg2f: fused softmax+aggregate (single head), LDS-staged weights =======
__global__ __launch_bounds__(256)
void agg2f_kernel(const float* __restrict__ feat,
                  const float* __restrict__ el, const float* __restrict__ er,
                  const int* __restrict__ srcs, const int* __restrict__ rowptr,
                  const float* __restrict__ bias, float* __restrict__ out, int N) {
  __shared__ float wlds[4][256];
  int wv = threadIdx.x >> 6;
  int n = blockIdx.x * 4 + wv;
  if (n >= N) return;
  int lane = threadIdx.x & 63;
  int p0 = rowptr[n], p1 = rowptr[n + 1];
  int deg = p1 - p0;
  float ern = er[n];
  float* wl = wlds[wv];
  float acc = 0.f;
  if (deg <= 256) {
    float ev[4];
    float m = -3.4e38f;
    #pragma unroll
    for (int st = 0; st < 4; ++st) {
      int i = p0 + st * 64 + lane;
      float e = -3.4e38f;
      if (i < p1) e = lrelu(el[srcs[i]] + ern);
      ev[st] = e; m = fmaxf(m, e);
    }
    #pragma unroll
    for (int s = 1; s <= 32; s <<= 1) m = fmaxf(m, __shfl_xor(m, s));
    float z = 0.f;
    #pragma unroll
    for (int st = 0; st < 4; ++st) { ev[st] = __expf(ev[st] - m); z += ev[st]; }
    #pragma unroll
    for (int s = 1; s <= 32; s <<= 1) z += __shfl_xor(z, s);
    float iz = (deg > 0) ? 1.f / z : 0.f;
    #pragma unroll
    for (int st = 0; st < 4; ++st) wl[st * 64 + lane] = ev[st] * iz;
    asm volatile("s_waitcnt lgkmcnt(0)" ::: "memory");
    int i = p0, sl = 0;
    for (; i + 4 <= p1; i += 4, sl += 4) {
      float w0 = wl[sl], w1 = wl[sl + 1], w2 = wl[sl + 2], w3 = wl[sl + 3];
      int s0 = srcs[i], s1 = srcs[i + 1], s2 = srcs[i + 2], s3 = srcs[i + 3];
      acc = fmaf(feat[(size_t)s0 * 64 + lane], w0, acc);
      acc = fmaf(feat[(size_t)s1 * 64 + lane], w1, acc);
      acc = fmaf(feat[(size_t)s2 * 64 + lane], w2, acc);
      acc = fmaf(feat[(size_t)s3 * 64 + lane], w3, acc);
    }
    for (; i < p1; ++i, ++sl)
      acc = fmaf(feat[(size_t)srcs[i] * 64 + lane], wl[sl], acc);
  } else {
    float m = -3.4e38f;
    for (int i = p0 + lane; i < p1; i += 64)
      m = fmaxf(m, lrelu(el[srcs[i]] + ern));
    #pragma unroll
    for (int s = 1; s <= 32; s <<= 1) m = fmaxf(m, __shfl_xor(m, s));
    float z = 0.f;
    for (int i = p0 + lane; i < p1; i += 64)
      z += __expf(lrelu(el[srcs[i]] + ern) - m);
    #pragma unroll
    for (int s = 1; s <= 32; s <<= 1) z += __shfl_xor(z, s);
    float iz = 1.f / z;
    for (int i = p0; i < p1; ++i) {
      int s0 = srcs[i];
      float w = __expf(lrelu(el[s0] + ern) - m) * iz;
      acc = fmaf(feat[(size_t)s0 * 64 + lane], w, acc);
    }
  }
  out[(size_t)n * 64 + lane] = acc + bias[lane];
}

extern "C" void kernel_launch(void* const* d_in, const int* in_sizes, int n_in,
                              void* d_out, int out_size, void* d_ws, size_t ws_size,
                              hipStream_t stream) {
  const float* x   = (const float*)d_in[0];
  const int*   src = (const int*)d_in[1];
  const int*   dst = (const int*)d_in[2];
  const float* W1  = (const float*)d_in[3];
  const float* al1 = (const float*)d_in[4];
  const float* ar1 = (const float*)d_in[5];
  const float* b1  = (const float*)d_in[6];
  const float* W2  = (const float*)d_in[7];
  const float* al2 = (const float*)d_in[8];
  const float* ar2 = (const float*)d_in[9];
  const float* b2  = (const float*)d_in[10];
  float* out = (float*)d_out;

  char* p = (char*)d_ws;
  auto alloc = [&](size_t bytes) { void* r = (void*)p; p += (bytes + 255) & ~(size_t)255; return r; };
  unsigned short* xb    = (unsigned short*)alloc((size_t)NN * 128 * 2);  // x bf16
  unsigned short* w1t   = (unsigned short*)alloc((size_t)512 * 128 * 2); // W1^T bf16
  unsigned short* w2t   = (unsigned short*)alloc((size_t)64 * 512 * 2);  // W2^T bf16
  unsigned short* feat1 = (unsigned short*)alloc((size_t)NN * 512 * 2);
  unsigned short* out1e = (unsigned short*)alloc((size_t)NN * 512 * 2);  // ELU applied
  float* el1   = (float*)alloc((size_t)NN * 8 * 4);
  float* er1   = (float*)alloc((size_t)NN * 8 * 4);
  float* feat2 = (float*)alloc((size_t)NN * 64 * 4);
  float* el2   = (float*)alloc((size_t)NN * 4);
  float* er2   = (float*)alloc((size_t)NN * 4);
  int* rowptr  = (int*)alloc((size_t)(NN + 1) * 4);
  int* srcs    = (int*)alloc((size_t)NE * 4);
  int* cnt     = (int*)alloc((size_t)NN * 4);
  int* fill    = (int*)alloc((size_t)NN * 4);

  hipMemsetAsync(cnt, 0, (size_t)NN * 4, stream);
  hipMemsetAsync(fill, 0, (size_t)NN * 4, stream);

  // prep converts
  cvt_x_kernel<<<(NN * 128 / 8 + 255) / 256, 256, 0, stream>>>(x, xb);
  cvt_wt_kernel<128, 512><<<(128 * 512 + 255) / 256, 256, 0, stream>>>(W1, w1t);
  cvt_wt_kernel<512, 64><<<(512 * 64 + 255) / 256, 256, 0, stream>>>(W2, w2t);

  // CSR build (shared by both layers)
  hist_kernel<<<(NE + 255) / 256, 256, 0, stream>>>(dst, cnt, NE);
  scan_kernel<<<1, 1024, 0, stream>>>(cnt, rowptr, NN);
  scatter_kernel<<<(NE + 255) / 256, 256, 0, stream>>>(dst, src, rowptr, fill, srcs, NE);

  // layer 1
  gemm1_mfma<<<dim3(391, 4), 256, 0, stream>>>(xb, w1t, al1, ar1, feat1, el1, er1);
  agg1f_kernel<<<(NN + 3) / 4, 256, 0, stream>>>(feat1, el1, er1, srcs, rowptr, b1, out1e, NN);

  // layer 2
  gemm2_mfma<<<391, 256, 0, stream>>>(out1e, w2t, al2, ar2, feat2, el2, er2);
  agg2f_kernel<<<(NN + 3) / 4, 256, 0, stream>>>(feat2, el2, er2, srcs, rowptr, b2, out, NN);
}